// Round 1
// baseline (204.518 us; speedup 1.0000x reference)
//
#include <hip/hip_runtime.h>

#define B_ 16
#define K_ 20
#define C_ 3
#define H_ 256
#define W_ 256
#define HW_ (H_*W_)
#define RAD 4
#define TH_ 64   // rows per strip in fused kernel

__global__ __launch_bounds__(256) void zero_ws_k(float* ws, int n) {
    int i = blockIdx.x * 256 + threadIdx.x;
    if (i < n) ws[i] = 0.f;
}

// Per-(b,k) sums: sum(labels), sum(labels*inputs_c) for c=0..2.
// grid (4 row-chunks, K, B), block 256 (one thread per column).
__global__ __launch_bounds__(256) void stats_k(const float* __restrict__ labels,
                                               const float* __restrict__ inputs,
                                               float* __restrict__ sums) {
    const int x = threadIdx.x;
    const int chunk = blockIdx.x;
    const int k = blockIdx.y;
    const int b = blockIdx.z;
    const int r0 = chunk * 64;
    const size_t lab_base = ((size_t)(b * K_ + k)) * HW_;
    const size_t in_base  = ((size_t)b) * C_ * HW_;
    float sl = 0.f, s0 = 0.f, s1 = 0.f, s2 = 0.f;
    for (int r = r0; r < r0 + 64; ++r) {
        int off = r * W_ + x;
        float l  = labels[lab_base + off];
        float i0 = inputs[in_base + off];
        float i1 = inputs[in_base + HW_ + off];
        float i2 = inputs[in_base + 2 * HW_ + off];
        sl += l; s0 += l * i0; s1 += l * i1; s2 += l * i2;
    }
    for (int o = 32; o > 0; o >>= 1) {
        sl += __shfl_down(sl, o); s0 += __shfl_down(s0, o);
        s1 += __shfl_down(s1, o); s2 += __shfl_down(s2, o);
    }
    __shared__ float rb[4][4];
    int wid = x >> 6, lane = x & 63;
    if (lane == 0) { rb[0][wid] = sl; rb[1][wid] = s0; rb[2][wid] = s1; rb[3][wid] = s2; }
    __syncthreads();
    if (x == 0) {
        int bk = b * K_ + k;
        atomicAdd(&sums[bk],               rb[0][0] + rb[0][1] + rb[0][2] + rb[0][3]);
        atomicAdd(&sums[B_*K_ + bk],       rb[1][0] + rb[1][1] + rb[1][2] + rb[1][3]);
        atomicAdd(&sums[2*B_*K_ + bk],     rb[2][0] + rb[2][1] + rb[2][2] + rb[2][3]);
        atomicAdd(&sums[3*B_*K_ + bk],     rb[3][0] + rb[3][1] + rb[3][2] + rb[3][3]);
    }
}

// Fused: weights -> separable 9x9 blur (vertical via register ring, horizontal
// via LDS row buffer) -> labels * blurred -> per-class num/den accumulation.
// grid (H/TH strips, K, B), block 256 (one thread per column).
__global__ __launch_bounds__(256) void fused_k(const float* __restrict__ labels,
                                               const float* __restrict__ inputs,
                                               const float* __restrict__ sums,
                                               float* __restrict__ numden) {
    const int x = threadIdx.x;
    const int strip = blockIdx.x;
    const int k = blockIdx.y;
    const int b = blockIdx.z;
    const int bk = b * K_ + k;

    // class mean from sums: cm = sum(l*i) / (sum(l) + 1e-5*HW)
    const float dn  = sums[bk] + 1e-5f * (float)HW_;
    const float cm0 = sums[B_*K_ + bk]   / dn;
    const float cm1 = sums[2*B_*K_ + bk] / dn;
    const float cm2 = sums[3*B_*K_ + bk] / dn;
    const float m2  = cm0*cm0 + cm1*cm1 + cm2*cm2;

    float g[9];
#pragma unroll
    for (int i = 0; i < 9; ++i) { float d = (float)(i - 4); g[i] = __expf(-d * d * (1.f / 50.f)); }

    __shared__ float svw[2][W_ + 2*RAD];
    __shared__ float svlw[2][W_ + 2*RAD];
    if (x < RAD) {
        svw[0][x] = 0.f;  svw[0][W_ + RAD + x] = 0.f;
        svw[1][x] = 0.f;  svw[1][W_ + RAD + x] = 0.f;
        svlw[0][x] = 0.f; svlw[0][W_ + RAD + x] = 0.f;
        svlw[1][x] = 0.f; svlw[1][W_ + RAD + x] = 0.f;
    }

    const size_t lab_base = ((size_t)bk) * HW_;
    const size_t in_base  = ((size_t)b) * C_ * HW_;
    const int r0 = strip * TH_;

    float wv[9], lwv[9], lab[9];

    auto load_row = [&](int gr, float& w_, float& lw_, float& l_) {
        w_ = 0.f; lw_ = 0.f; l_ = 0.f;
        if (gr >= 0 && gr < H_) {
            int off = gr * W_ + x;
            float l  = labels[lab_base + off];
            float i0 = inputs[in_base + off];
            float i1 = inputs[in_base + HW_ + off];
            float i2 = inputs[in_base + 2 * HW_ + off];
            float df = (i0*i0 + i1*i1 + i2*i2) - 2.f * (i0*cm0 + i1*cm1 + i2*cm2) + m2;
            float wgt = __expf(-df * df);   // SIGMA_2 = 1
            w_ = wgt; lw_ = l * wgt; l_ = l;
        }
    };

#pragma unroll
    for (int i = 0; i < 8; ++i) load_row(r0 - RAD + i, wv[i], lwv[i], lab[i]);

    __syncthreads();  // pads visible before first horizontal pass

    float num = 0.f, den = 0.f;
    for (int rr = 0; rr < TH_; ++rr) {
        load_row(r0 + rr + RAD, wv[8], lwv[8], lab[8]);
        // vertical blur
        float a = 0.f, c = 0.f;
#pragma unroll
        for (int i = 0; i < 9; ++i) { a += g[i] * wv[i]; c += g[i] * lwv[i]; }
        const int bf = rr & 1;
        svw[bf][RAD + x]  = a;
        svlw[bf][RAD + x] = c;
        __syncthreads();
        // horizontal blur
        float hw = 0.f, hlw = 0.f;
#pragma unroll
        for (int i = 0; i < 9; ++i) { hw += g[i] * svw[bf][x + i]; hlw += g[i] * svlw[bf][x + i]; }
        float lc = lab[4];  // labels at the output row
        num += lc * hlw; den += lc * hw;
        // shift ring
#pragma unroll
        for (int i = 0; i < 8; ++i) { wv[i] = wv[i+1]; lwv[i] = lwv[i+1]; lab[i] = lab[i+1]; }
    }

    for (int o = 32; o > 0; o >>= 1) { num += __shfl_down(num, o); den += __shfl_down(den, o); }
    __shared__ float rb[2][4];
    int wid = x >> 6, lane = x & 63;
    __syncthreads();
    if (lane == 0) { rb[0][wid] = num; rb[1][wid] = den; }
    __syncthreads();
    if (x == 0) {
        atomicAdd(&numden[k],      rb[0][0] + rb[0][1] + rb[0][2] + rb[0][3]);
        atomicAdd(&numden[K_ + k], rb[1][0] + rb[1][1] + rb[1][2] + rb[1][3]);
    }
}

__global__ void finalize_k(const float* __restrict__ numden, float* __restrict__ out) {
    if (threadIdx.x == 0 && blockIdx.x == 0) {
        float loss = 0.f;
        for (int kk = 0; kk < K_; ++kk)
            loss += fabsf(numden[kk] / (numden[K_ + kk] + 1e-6f));
        out[0] = (float)K_ - loss;
    }
}

extern "C" void kernel_launch(void* const* d_in, const int* in_sizes, int n_in,
                              void* d_out, int out_size, void* d_ws, size_t ws_size,
                              hipStream_t stream) {
    const float* labels = (const float*)d_in[0];
    const float* inputs = (const float*)d_in[1];
    float* ws     = (float*)d_ws;
    float* sums   = ws;                 // 4 * B * K floats
    float* numden = ws + 4 * B_ * K_;   // 2 * K floats
    const int nz = 4 * B_ * K_ + 2 * K_;

    zero_ws_k<<<(nz + 255) / 256, 256, 0, stream>>>(ws, nz);
    stats_k<<<dim3(4, K_, B_), 256, 0, stream>>>(labels, inputs, sums);
    fused_k<<<dim3(H_ / TH_, K_, B_), 256, 0, stream>>>(labels, inputs, sums, numden);
    finalize_k<<<1, 64, 0, stream>>>(numden, (float*)d_out);
}